// Round 9
// baseline (136.583 us; speedup 1.0000x reference)
//
#include <hip/hip_runtime.h>

// R9 = MEASUREMENT: exact R3 source; tree512/tree16/tail launched 3x each
// (idempotent). dur = 73.3 + 2*(tree512+tree16+tail).
// Band ~85-92 -> trees small, fixed ~40us replay cost dominates (near floor).
// Band ~150-165 -> trees are the real 45us -> rebuild tree next.

#define NN 32767   // n_nodes
#define NL 16384   // n_leaves
#define DD 1024    // D
#define LL 32      // num labels

typedef __attribute__((ext_vector_type(8))) short bf16x8;
typedef __attribute__((ext_vector_type(4))) float f32x4;

__device__ __forceinline__ short f2bf(float f) {
  union { float f; unsigned u; } x; x.f = f;
  unsigned r = x.u + 0x7FFFu + ((x.u >> 16) & 1u);  // RNE
  return (short)(r >> 16);
}

__device__ __forceinline__ bf16x8 cvt8(float4 a, float4 b) {
  bf16x8 r;
  r[0] = f2bf(a.x); r[1] = f2bf(a.y); r[2] = f2bf(a.z); r[3] = f2bf(a.w);
  r[4] = f2bf(b.x); r[5] = f2bf(b.y); r[6] = f2bf(b.z); r[7] = f2bf(b.w);
  return r;
}

__device__ __forceinline__ void gld_lds16(const float* g, float* l) {
  __builtin_amdgcn_global_load_lds(
      (const __attribute__((address_space(1))) void*)g,
      (__attribute__((address_space(3))) void*)l, 16, 0, 0);
}

__global__ __launch_bounds__(256) void pack_kernel(const float* __restrict__ Wp,
                                                   short* __restrict__ Wpk) {
  int idx = blockIdx.x * 256 + threadIdx.x;   // grid 64 -> 16384 threads
  #pragma unroll
  for (int t = 0; t < 4; ++t, idx += 16384) {
    const int j = idx & 7, m = (idx >> 3) & 3, lane = (idx >> 5) & 63, s = idx >> 11;
    const int wrow = (lane & 15) + 16 * (m & 1);
    const int wcol = (m >> 1) * 1024 + s * 32 + (lane >> 4) * 8 + j;
    Wpk[idx] = f2bf(Wp[(size_t)wrow * (2 * DD) + wcol]);
  }
}

__global__ __launch_bounds__(256) void gemm_kernel(
    const float* __restrict__ hidden, const short* __restrict__ Wpk,
    float* __restrict__ E0, float* __restrict__ gpart) {
  __shared__ float lds[4 * 3 * 1024];           // 4 waves x 3 bufs x 4KB
  const int tid = threadIdx.x;
  const int wid = tid >> 6, lane = tid & 63;
  const int tile = blockIdx.x * 4 + wid;        // 0..2047, 16 rows each
  const int mrow = lane & 15, g = lane >> 4;
  const int swz = (mrow & 7) << 4;              // byte XOR for ds_read side
  float* ldsw = lds + wid * 3072;

  const float* ab0; const float* ab1; const float* ab2; const float* ab3;
  {
    const int lr = lane >> 4, lc16 = (lane & 15) * 16;
    #define MKAB(I, P) { const int row = (I)*4 + lr;                         \
      const int csrc = lc16 ^ ((row & 7) << 4);                              \
      int grow = tile * 16 + row; if (grow > NN - 1) grow = NN - 1;          \
      P = hidden + (size_t)grow * DD + (csrc >> 2); }
    MKAB(0, ab0) MKAB(1, ab1) MKAB(2, ab2) MKAB(3, ab3)
    #undef MKAB
  }
  const bf16x8* wbase = (const bf16x8*)Wpk + (size_t)lane * 4;

  const int cidx00 = ((g * 32) ^ swz) >> 2;
  const int cidx01 = ((g * 32 + 16) ^ swz) >> 2;
  const int cidx10 = ((128 + g * 32) ^ swz) >> 2;
  const int cidx11 = ((128 + g * 32 + 16) ^ swz) >> 2;

  f32x4 acc0 = {0,0,0,0}, acc1 = {0,0,0,0}, acc2 = {0,0,0,0}, acc3 = {0,0,0,0};

#define STAGE_A(KC) {                                   \
    float* ld_ = ldsw + ((KC) % 3) * 1024;              \
    gld_lds16(ab0 + (KC) * 64, ld_);                    \
    gld_lds16(ab1 + (KC) * 64, ld_ + 256);              \
    gld_lds16(ab2 + (KC) * 64, ld_ + 512);              \
    gld_lds16(ab3 + (KC) * 64, ld_ + 768); }

#define LOAD_W(KC, W0,W1,W2,W3, X0,X1,X2,X3) {          \
    const bf16x8* p_ = wbase + (size_t)(2 * (KC)) * 256; \
    W0 = p_[0];   W1 = p_[1];   W2 = p_[2];   W3 = p_[3]; \
    X0 = p_[256]; X1 = p_[257]; X2 = p_[258]; X3 = p_[259]; }

#define CHUNK(KC, VM, W0,W1,W2,W3, X0,X1,X2,X3)                              \
  { if ((KC) + 2 < 16) STAGE_A((KC) + 2)                                     \
    asm volatile("s_waitcnt vmcnt(" VM ")" ::: "memory");                    \
    { const float* bc = ldsw + ((KC) % 3) * 1024 + mrow * 64;                \
      float4 fa0 = *(const float4*)(bc + cidx00);                            \
      float4 fb0 = *(const float4*)(bc + cidx01);                            \
      bf16x8 af0 = cvt8(fa0, fb0);                                           \
      acc0 = __builtin_amdgcn_mfma_f32_16x16x32_bf16(af0, W0, acc0, 0,0,0);  \
      acc1 = __builtin_amdgcn_mfma_f32_16x16x32_bf16(af0, W1, acc1, 0,0,0);  \
      acc2 = __builtin_amdgcn_mfma_f32_16x16x32_bf16(af0, W2, acc2, 0,0,0);  \
      acc3 = __builtin_amdgcn_mfma_f32_16x16x32_bf16(af0, W3, acc3, 0,0,0);  \
      float4 fa1 = *(const float4*)(bc + cidx10);                            \
      float4 fb1 = *(const float4*)(bc + cidx11);                            \
      bf16x8 af1 = cvt8(fa1, fb1);                                           \
      acc0 = __builtin_amdgcn_mfma_f32_16x16x32_bf16(af1, X0, acc0, 0,0,0);  \
      acc1 = __builtin_amdgcn_mfma_f32_16x16x32_bf16(af1, X1, acc1, 0,0,0);  \
      acc2 = __builtin_amdgcn_mfma_f32_16x16x32_bf16(af1, X2, acc2, 0,0,0);  \
      acc3 = __builtin_amdgcn_mfma_f32_16x16x32_bf16(af1, X3, acc3, 0,0,0);  \
    }                                                                        \
    if ((KC) + 2 < 16) LOAD_W((KC) + 2, W0,W1,W2,W3, X0,X1,X2,X3) }

  bf16x8 u0,u1,u2,u3,u4,u5,u6,u7, v0,v1,v2,v3,v4,v5,v6,v7;
  STAGE_A(0) STAGE_A(1)
  LOAD_W(0, u0,u1,u2,u3, u4,u5,u6,u7)
  LOAD_W(1, v0,v1,v2,v3, v4,v5,v6,v7)
  CHUNK( 0, "24", u0,u1,u2,u3, u4,u5,u6,u7)
  CHUNK( 1, "32", v0,v1,v2,v3, v4,v5,v6,v7)
  CHUNK( 2, "24", u0,u1,u2,u3, u4,u5,u6,u7)
  CHUNK( 3, "24", v0,v1,v2,v3, v4,v5,v6,v7)
  CHUNK( 4, "24", u0,u1,u2,u3, u4,u5,u6,u7)
  CHUNK( 5, "24", v0,v1,v2,v3, v4,v5,v6,v7)
  CHUNK( 6, "24", u0,u1,u2,u3, u4,u5,u6,u7)
  CHUNK( 7, "24", v0,v1,v2,v3, v4,v5,v6,v7)
  CHUNK( 8, "24", u0,u1,u2,u3, u4,u5,u6,u7)
  CHUNK( 9, "24", v0,v1,v2,v3, v4,v5,v6,v7)
  CHUNK(10, "24", u0,u1,u2,u3, u4,u5,u6,u7)
  CHUNK(11, "24", v0,v1,v2,v3, v4,v5,v6,v7)
  CHUNK(12, "24", u0,u1,u2,u3, u4,u5,u6,u7)
  CHUNK(13, "24", v0,v1,v2,v3, v4,v5,v6,v7)
  CHUNK(14, "20", u0,u1,u2,u3, u4,u5,u6,u7)
  CHUNK(15, "8",  v0,v1,v2,v3, v4,v5,v6,v7)
#undef CHUNK
#undef LOAD_W
#undef STAGE_A

  #pragma unroll
  for (int r = 0; r < 4; ++r) {
    const int srow = tile * 16 + g * 4 + r;
    if (srow < NN) {
      E0[(size_t)srow * LL + mrow]      = acc0[r];
      E0[(size_t)srow * LL + mrow + 16] = acc1[r];
    }
  }
  if (tile == 2047 && g == 3) { acc2[3] = 0.f; acc3[3] = 0.f; }
  float s2 = acc2[0] + acc2[1] + acc2[2] + acc2[3];
  float s3 = acc3[0] + acc3[1] + acc3[2] + acc3[3];
  s2 += __shfl_xor(s2, 16, 64); s2 += __shfl_xor(s2, 32, 64);
  s3 += __shfl_xor(s3, 16, 64); s3 += __shfl_xor(s3, 32, 64);
  if (lane < 32) gpart[(size_t)tile * LL + lane] = (lane < 16) ? s2 : s3;
}

__global__ __launch_bounds__(256) void cvec_kernel(
    const float* __restrict__ bp, const float* __restrict__ gpart,
    float* __restrict__ cvec) {
  const int col = blockIdx.x;
  const int tid = threadIdx.x, wid = tid >> 6, lane = tid & 63;
  float s = 0.f;
  for (int w = tid; w < 2048; w += 256) s += gpart[(size_t)w * LL + col];
  #pragma unroll
  for (int m = 1; m <= 32; m <<= 1) s += __shfl_xor(s, m, 64);
  __shared__ float red[4];
  if (lane == 0) red[wid] = s;
  __syncthreads();
  if (tid == 0)
    cvec[col] = bp[col] + (red[0] + red[1] + red[2] + red[3]) * (1.0f / (float)NN);
}

__device__ __forceinline__ float lse32(const float4* tt, const float4* sv) {
  float m = -3.0e38f;
  float4 v[8];
  #pragma unroll
  for (int i = 0; i < 8; ++i) {
    float4 t = tt[i], s = sv[i], w;
    w.x = t.x + s.x; w.y = t.y + s.y; w.z = t.z + s.z; w.w = t.w + s.w;
    v[i] = w;
    m = fmaxf(m, fmaxf(fmaxf(w.x, w.y), fmaxf(w.z, w.w)));
  }
  float ss = 0.f;
  #pragma unroll
  for (int i = 0; i < 8; ++i) {
    ss += __expf(v[i].x - m) + __expf(v[i].y - m) +
          __expf(v[i].z - m) + __expf(v[i].w - m);
  }
  return m + __logf(ss);
}

__global__ __launch_bounds__(1024) void tree_kernel(
    const float* __restrict__ E0, const float* __restrict__ cvec,
    const float* __restrict__ trans, const float* __restrict__ src,
    float* __restrict__ dst, int base1, int leafmode) {
  __shared__ float l1[16][LL], l2[8][LL], l3[4][LL];
  const int wid = threadIdx.x >> 6, lane = threadIdx.x & 63;
  const int j = lane & 31, half = lane >> 5;
  const int b = blockIdx.x, G = gridDim.x;
  float4 tt[8];
  #pragma unroll
  for (int i = 0; i < 8; ++i) tt[i] = *(const float4*)(trans + j * LL + i * 4);
  const float cj = cvec[j];
  float4 sv[8];

  { // phase 1
    const int n = b * 16 + wid;
    const float* sp = src + (size_t)(2 * n + half) * LL;
    if (leafmode) {
      #pragma unroll
      for (int i = 0; i < 8; ++i) {
        float4 vv = *(const float4*)(sp + i * 4);
        float4 c4 = *(const float4*)(cvec + i * 4);
        vv.x += c4.x; vv.y += c4.y; vv.z += c4.z; vv.w += c4.w;
        sv[i] = vv;
      }
    } else {
      #pragma unroll
      for (int i = 0; i < 8; ++i) sv[i] = *(const float4*)(sp + i * 4);
    }
    float lsum = lse32(tt, sv);
    float other = __shfl_xor(lsum, 32, 64);
    float o = E0[(size_t)(base1 + n) * LL + j] + cj + lsum + other;
    if (lane < 32) l1[wid][j] = o;
  }
  __syncthreads();
  const int base2 = base1 + G * 16;
  if (wid < 8) { // phase 2
    const float* sp = l1[2 * wid + half];
    #pragma unroll
    for (int i = 0; i < 8; ++i) sv[i] = *(const float4*)(sp + i * 4);
    float lsum = lse32(tt, sv);
    float other = __shfl_xor(lsum, 32, 64);
    float o = E0[(size_t)(base2 + b * 8 + wid) * LL + j] + cj + lsum + other;
    if (lane < 32) l2[wid][j] = o;
  }
  __syncthreads();
  const int base3 = base2 + G * 8;
  if (wid < 4) { // phase 3
    const float* sp = l2[2 * wid + half];
    #pragma unroll
    for (int i = 0; i < 8; ++i) sv[i] = *(const float4*)(sp + i * 4);
    float lsum = lse32(tt, sv);
    float other = __shfl_xor(lsum, 32, 64);
    float o = E0[(size_t)(base3 + b * 4 + wid) * LL + j] + cj + lsum + other;
    if (lane < 32) l3[wid][j] = o;
  }
  __syncthreads();
  const int base4 = base3 + G * 4;
  if (wid < 2) { // phase 4
    const float* sp = l3[2 * wid + half];
    #pragma unroll
    for (int i = 0; i < 8; ++i) sv[i] = *(const float4*)(sp + i * 4);
    float lsum = lse32(tt, sv);
    float other = __shfl_xor(lsum, 32, 64);
    float o = E0[(size_t)(base4 + b * 2 + wid) * LL + j] + cj + lsum + other;
    if (lane < 32) l1[wid][j] = o;
  }
  __syncthreads();
  const int base5 = base4 + G * 2;
  if (wid == 0) { // phase 5
    const float* sp = l1[half];
    #pragma unroll
    for (int i = 0; i < 8; ++i) sv[i] = *(const float4*)(sp + i * 4);
    float lsum = lse32(tt, sv);
    float other = __shfl_xor(lsum, 32, 64);
    float o = E0[(size_t)(base5 + b) * LL + j] + cj + lsum + other;
    if (lane < 32) dst[(size_t)b * LL + j] = o;
  }
}

__global__ __launch_bounds__(512) void tail_kernel(
    const float* __restrict__ E0, const float* __restrict__ cvec,
    const float* __restrict__ trans, const float* __restrict__ S10,
    float* __restrict__ out) {
  __shared__ float t1[8][LL], t2[4][LL], t3[2][LL];
  const int wid = threadIdx.x >> 6, lane = threadIdx.x & 63;
  const int j = lane & 31, half = lane >> 5;
  float4 tt[8];
  #pragma unroll
  for (int i = 0; i < 8; ++i) tt[i] = *(const float4*)(trans + j * LL + i * 4);
  const float cj = cvec[j];
  float4 sv[8];

  { // width 8
    const float* sp = S10 + (size_t)(2 * wid + half) * LL;
    #pragma unroll
    for (int i = 0; i < 8; ++i) sv[i] = *(const float4*)(sp + i * 4);
    float lsum = lse32(tt, sv);
    float other = __shfl_xor(lsum, 32, 64);
    float o = E0[(size_t)(32752 + wid) * LL + j] + cj + lsum + other;
    if (lane < 32) t1[wid][j] = o;
  }
  __syncthreads();
  if (wid < 4) { // width 4
    const float* sp = t1[2 * wid + half];
    #pragma unroll
    for (int i = 0; i < 8; ++i) sv[i] = *(const float4*)(sp + i * 4);
    float lsum = lse32(tt, sv);
    float other = __shfl_xor(lsum, 32, 64);
    float o = E0[(size_t)(32760 + wid) * LL + j] + cj + lsum + other;
    if (lane < 32) t2[wid][j] = o;
  }
  __syncthreads();
  if (wid < 2) { // width 2
    const float* sp = t2[2 * wid + half];
    #pragma unroll
    for (int i = 0; i < 8; ++i) sv[i] = *(const float4*)(sp + i * 4);
    float lsum = lse32(tt, sv);
    float other = __shfl_xor(lsum, 32, 64);
    float o = E0[(size_t)(32764 + wid) * LL + j] + cj + lsum + other;
    if (lane < 32) t3[wid][j] = o;
  }
  __syncthreads();
  if (wid == 0) { // root = node 32766
    const float* sp = t3[half];
    #pragma unroll
    for (int i = 0; i < 8; ++i) sv[i] = *(const float4*)(sp + i * 4);
    float lsum = lse32(tt, sv);
    float other = __shfl_xor(lsum, 32, 64);
    float o = E0[(size_t)32766 * LL + j] + cj + lsum + other;
    if (lane < 32) out[j] = o;
  }
}

extern "C" void kernel_launch(void* const* d_in, const int* in_sizes, int n_in,
                              void* d_out, int out_size, void* d_ws, size_t ws_size,
                              hipStream_t stream) {
  const float* hidden = (const float*)d_in[0];
  const float* trans  = (const float*)d_in[1];
  const float* Wp     = (const float*)d_in[2];
  const float* bp     = (const float*)d_in[3];

  float* ws    = (float*)d_ws;
  float* E0    = ws;                               // NN*32 f32
  float* gpart = E0 + (size_t)NN * LL;             // 2048*32 f32
  float* cvecb = gpart + (size_t)2048 * LL;        // 32 f32
  float* S5    = cvecb + 32;                       // 512*32 f32
  float* S10   = S5 + 512 * LL;                    // 16*32 f32
  short* Wpk   = (short*)(S10 + 16 * LL);          // 65536 bf16

  pack_kernel<<<64, 256, 0, stream>>>(Wp, Wpk);
  gemm_kernel<<<512, 256, 0, stream>>>(hidden, Wpk, E0, gpart);
  cvec_kernel<<<32, 256, 0, stream>>>(bp, gpart, cvecb);
  // MEASUREMENT: each tree kernel 3x (idempotent).
  tree_kernel<<<512, 1024, 0, stream>>>(E0, cvecb, trans, E0, S5, 16384, 1);
  tree_kernel<<<512, 1024, 0, stream>>>(E0, cvecb, trans, E0, S5, 16384, 1);
  tree_kernel<<<512, 1024, 0, stream>>>(E0, cvecb, trans, E0, S5, 16384, 1);
  tree_kernel<<<16, 1024, 0, stream>>>(E0, cvecb, trans, S5, S10, 32256, 0);
  tree_kernel<<<16, 1024, 0, stream>>>(E0, cvecb, trans, S5, S10, 32256, 0);
  tree_kernel<<<16, 1024, 0, stream>>>(E0, cvecb, trans, S5, S10, 32256, 0);
  tail_kernel<<<1, 512, 0, stream>>>(E0, cvecb, trans, S10, (float*)d_out);
  tail_kernel<<<1, 512, 0, stream>>>(E0, cvecb, trans, S10, (float*)d_out);
  tail_kernel<<<1, 512, 0, stream>>>(E0, cvecb, trans, S10, (float*)d_out);
}

// Round 10
// 81.254 us; speedup vs baseline: 1.6809x; 1.6809x over previous
//
#include <hip/hip_runtime.h>

// R10: pack/gemm/cvec byte-identical R3 (gemm=24.4us, frozen). Tree rebuilt:
// distributed-row layout (1 elem/lane), expT matvec-lse (1 exp/lane/node vs 32),
// es shared via wave-private LDS row. tree16+tail merged -> 5 launches.

#define NN 32767   // n_nodes
#define NL 16384   // n_leaves
#define DD 1024    // D
#define LL 32      // num labels

typedef __attribute__((ext_vector_type(8))) short bf16x8;
typedef __attribute__((ext_vector_type(4))) float f32x4;

__device__ __forceinline__ short f2bf(float f) {
  union { float f; unsigned u; } x; x.f = f;
  unsigned r = x.u + 0x7FFFu + ((x.u >> 16) & 1u);  // RNE
  return (short)(r >> 16);
}

__device__ __forceinline__ bf16x8 cvt8(float4 a, float4 b) {
  bf16x8 r;
  r[0] = f2bf(a.x); r[1] = f2bf(a.y); r[2] = f2bf(a.z); r[3] = f2bf(a.w);
  r[4] = f2bf(b.x); r[5] = f2bf(b.y); r[6] = f2bf(b.z); r[7] = f2bf(b.w);
  return r;
}

__device__ __forceinline__ void gld_lds16(const float* g, float* l) {
  __builtin_amdgcn_global_load_lds(
      (const __attribute__((address_space(1))) void*)g,
      (__attribute__((address_space(3))) void*)l, 16, 0, 0);
}

__global__ __launch_bounds__(256) void pack_kernel(const float* __restrict__ Wp,
                                                   short* __restrict__ Wpk) {
  int idx = blockIdx.x * 256 + threadIdx.x;   // grid 64 -> 16384 threads
  #pragma unroll
  for (int t = 0; t < 4; ++t, idx += 16384) {
    const int j = idx & 7, m = (idx >> 3) & 3, lane = (idx >> 5) & 63, s = idx >> 11;
    const int wrow = (lane & 15) + 16 * (m & 1);
    const int wcol = (m >> 1) * 1024 + s * 32 + (lane >> 4) * 8 + j;
    Wpk[idx] = f2bf(Wp[(size_t)wrow * (2 * DD) + wcol]);
  }
}

__global__ __launch_bounds__(256) void gemm_kernel(
    const float* __restrict__ hidden, const short* __restrict__ Wpk,
    float* __restrict__ E0, float* __restrict__ gpart) {
  __shared__ float lds[4 * 3 * 1024];           // 4 waves x 3 bufs x 4KB
  const int tid = threadIdx.x;
  const int wid = tid >> 6, lane = tid & 63;
  const int tile = blockIdx.x * 4 + wid;        // 0..2047, 16 rows each
  const int mrow = lane & 15, g = lane >> 4;
  const int swz = (mrow & 7) << 4;              // byte XOR for ds_read side
  float* ldsw = lds + wid * 3072;

  const float* ab0; const float* ab1; const float* ab2; const float* ab3;
  {
    const int lr = lane >> 4, lc16 = (lane & 15) * 16;
    #define MKAB(I, P) { const int row = (I)*4 + lr;                         \
      const int csrc = lc16 ^ ((row & 7) << 4);                              \
      int grow = tile * 16 + row; if (grow > NN - 1) grow = NN - 1;          \
      P = hidden + (size_t)grow * DD + (csrc >> 2); }
    MKAB(0, ab0) MKAB(1, ab1) MKAB(2, ab2) MKAB(3, ab3)
    #undef MKAB
  }
  const bf16x8* wbase = (const bf16x8*)Wpk + (size_t)lane * 4;

  const int cidx00 = ((g * 32) ^ swz) >> 2;
  const int cidx01 = ((g * 32 + 16) ^ swz) >> 2;
  const int cidx10 = ((128 + g * 32) ^ swz) >> 2;
  const int cidx11 = ((128 + g * 32 + 16) ^ swz) >> 2;

  f32x4 acc0 = {0,0,0,0}, acc1 = {0,0,0,0}, acc2 = {0,0,0,0}, acc3 = {0,0,0,0};

#define STAGE_A(KC) {                                   \
    float* ld_ = ldsw + ((KC) % 3) * 1024;              \
    gld_lds16(ab0 + (KC) * 64, ld_);                    \
    gld_lds16(ab1 + (KC) * 64, ld_ + 256);              \
    gld_lds16(ab2 + (KC) * 64, ld_ + 512);              \
    gld_lds16(ab3 + (KC) * 64, ld_ + 768); }

#define LOAD_W(KC, W0,W1,W2,W3, X0,X1,X2,X3) {          \
    const bf16x8* p_ = wbase + (size_t)(2 * (KC)) * 256; \
    W0 = p_[0];   W1 = p_[1];   W2 = p_[2];   W3 = p_[3]; \
    X0 = p_[256]; X1 = p_[257]; X2 = p_[258]; X3 = p_[259]; }

#define CHUNK(KC, VM, W0,W1,W2,W3, X0,X1,X2,X3)                              \
  { if ((KC) + 2 < 16) STAGE_A((KC) + 2)                                     \
    asm volatile("s_waitcnt vmcnt(" VM ")" ::: "memory");                    \
    { const float* bc = ldsw + ((KC) % 3) * 1024 + mrow * 64;                \
      float4 fa0 = *(const float4*)(bc + cidx00);                            \
      float4 fb0 = *(const float4*)(bc + cidx01);                            \
      bf16x8 af0 = cvt8(fa0, fb0);                                           \
      acc0 = __builtin_amdgcn_mfma_f32_16x16x32_bf16(af0, W0, acc0, 0,0,0);  \
      acc1 = __builtin_amdgcn_mfma_f32_16x16x32_bf16(af0, W1, acc1, 0,0,0);  \
      acc2 = __builtin_amdgcn_mfma_f32_16x16x32_bf16(af0, W2, acc2, 0,0,0);  \
      acc3 = __builtin_amdgcn_mfma_f32_16x16x32_bf16(af0, W3, acc3, 0,0,0);  \
      float4 fa1 = *(const float4*)(bc + cidx10);                            \
      float4 fb1 = *(const float4*)(bc + cidx11);                            \
      bf16x8 af1 = cvt8(fa1, fb1);                                           \
      acc0 = __builtin_amdgcn_mfma_f32_16x16x32_bf16(af1, X0, acc0, 0,0,0);  \
      acc1 = __builtin_amdgcn_mfma_f32_16x16x32_bf16(af1, X1, acc1, 0,0,0);  \
      acc2 = __builtin_amdgcn_mfma_f32_16x16x32_bf16(af1, X2, acc2, 0,0,0);  \
      acc3 = __builtin_amdgcn_mfma_f32_16x16x32_bf16(af1, X3, acc3, 0,0,0);  \
    }                                                                        \
    if ((KC) + 2 < 16) LOAD_W((KC) + 2, W0,W1,W2,W3, X0,X1,X2,X3) }

  bf16x8 u0,u1,u2,u3,u4,u5,u6,u7, v0,v1,v2,v3,v4,v5,v6,v7;
  STAGE_A(0) STAGE_A(1)
  LOAD_W(0, u0,u1,u2,u3, u4,u5,u6,u7)
  LOAD_W(1, v0,v1,v2,v3, v4,v5,v6,v7)
  CHUNK( 0, "24", u0,u1,u2,u3, u4,u5,u6,u7)
  CHUNK( 1, "32", v0,v1,v2,v3, v4,v5,v6,v7)
  CHUNK( 2, "24", u0,u1,u2,u3, u4,u5,u6,u7)
  CHUNK( 3, "24", v0,v1,v2,v3, v4,v5,v6,v7)
  CHUNK( 4, "24", u0,u1,u2,u3, u4,u5,u6,u7)
  CHUNK( 5, "24", v0,v1,v2,v3, v4,v5,v6,v7)
  CHUNK( 6, "24", u0,u1,u2,u3, u4,u5,u6,u7)
  CHUNK( 7, "24", v0,v1,v2,v3, v4,v5,v6,v7)
  CHUNK( 8, "24", u0,u1,u2,u3, u4,u5,u6,u7)
  CHUNK( 9, "24", v0,v1,v2,v3, v4,v5,v6,v7)
  CHUNK(10, "24", u0,u1,u2,u3, u4,u5,u6,u7)
  CHUNK(11, "24", v0,v1,v2,v3, v4,v5,v6,v7)
  CHUNK(12, "24", u0,u1,u2,u3, u4,u5,u6,u7)
  CHUNK(13, "24", v0,v1,v2,v3, v4,v5,v6,v7)
  CHUNK(14, "20", u0,u1,u2,u3, u4,u5,u6,u7)
  CHUNK(15, "8",  v0,v1,v2,v3, v4,v5,v6,v7)
#undef CHUNK
#undef LOAD_W
#undef STAGE_A

  #pragma unroll
  for (int r = 0; r < 4; ++r) {
    const int srow = tile * 16 + g * 4 + r;
    if (srow < NN) {
      E0[(size_t)srow * LL + mrow]      = acc0[r];
      E0[(size_t)srow * LL + mrow + 16] = acc1[r];
    }
  }
  if (tile == 2047 && g == 3) { acc2[3] = 0.f; acc3[3] = 0.f; }
  float s2 = acc2[0] + acc2[1] + acc2[2] + acc2[3];
  float s3 = acc3[0] + acc3[1] + acc3[2] + acc3[3];
  s2 += __shfl_xor(s2, 16, 64); s2 += __shfl_xor(s2, 32, 64);
  s3 += __shfl_xor(s3, 16, 64); s3 += __shfl_xor(s3, 32, 64);
  if (lane < 32) gpart[(size_t)tile * LL + lane] = (lane < 16) ? s2 : s3;
}

__global__ __launch_bounds__(256) void cvec_kernel(
    const float* __restrict__ bp, const float* __restrict__ gpart,
    float* __restrict__ cvec) {
  const int col = blockIdx.x;
  const int tid = threadIdx.x, wid = tid >> 6, lane = tid & 63;
  float s = 0.f;
  for (int w = tid; w < 2048; w += 256) s += gpart[(size_t)w * LL + col];
  #pragma unroll
  for (int m = 1; m <= 32; m <<= 1) s += __shfl_xor(s, m, 64);
  __shared__ float red[4];
  if (lane == 0) red[wid] = s;
  __syncthreads();
  if (tid == 0)
    cvec[col] = bp[col] + (red[0] + red[1] + red[2] + red[3]) * (1.0f / (float)NN);
}

// ---------------- new tree machinery ----------------
// Layout: child row distributed 1 element/lane (lanes 0-31 = left child,
// 32-63 = right child; k = lane&31). lse via expT matvec:
//   lse_k(T[j,k]+s[k]) = m + log(sum_k expT[j,k] * exp(s[k]-m)), m = max_k s[k].
// Per node: 1 exp/lane, es shared via wave-private LDS row (broadcast reads).

// cs: this half's child element k; ep: E0[parent][j]; returns full output o[j].
__device__ __forceinline__ float node_combine(float cs, float ep, float cvj,
                                              const float4* etr, float* eswb,
                                              int lane) {
  float m = cs;
  #pragma unroll
  for (int d = 1; d <= 16; d <<= 1) m = fmaxf(m, __shfl_xor(m, d, 64));
  float es = __expf(cs - m);
  eswb[lane] = es;
  asm volatile("s_waitcnt lgkmcnt(0)" ::: "memory");
  __builtin_amdgcn_sched_barrier(0);
  const float4* eb = (const float4*)(eswb + (lane & 32));  // this half's 32 es
  float a0 = 0.f, a1 = 0.f, a2 = 0.f, a3 = 0.f;
  #pragma unroll
  for (int i = 0; i < 8; i += 2) {
    float4 e0 = eb[i], e1 = eb[i + 1];
    float4 t0 = etr[i], t1 = etr[i + 1];
    a0 += t0.x * e0.x; a1 += t0.y * e0.y; a2 += t0.z * e0.z; a3 += t0.w * e0.w;
    a0 += t1.x * e1.x; a1 += t1.y * e1.y; a2 += t1.z * e1.z; a3 += t1.w * e1.w;
  }
  float dot = (a0 + a1) + (a2 + a3);
  float lseh = m + __logf(dot);
  float oth = __shfl_xor(lseh, 32, 64);
  return ep + cvj + lseh + oth;
}

#define LOAD_ETR(etr, trans, lane)                                        \
  _Pragma("unroll")                                                       \
  for (int i_ = 0; i_ < 8; ++i_) {                                        \
    float4 t_ = *(const float4*)((trans) + ((lane) & 31) * LL + i_ * 4);  \
    etr[i_].x = __expf(t_.x); etr[i_].y = __expf(t_.y);                   \
    etr[i_].z = __expf(t_.z); etr[i_].w = __expf(t_.w);                   \
  }

// T1: widths 8192..512. 512 blocks x 16 waves, 1 node/wave at phase 1.
__global__ __launch_bounds__(1024) void tree1_kernel(
    const float* __restrict__ E0, const float* __restrict__ cvec,
    const float* __restrict__ trans, float* __restrict__ S5) {
  __shared__ float esb[16][64];
  __shared__ float l1[16][LL], l2[8][LL], l3[4][LL], l4[2][LL];
  const int tid = threadIdx.x, w = tid >> 6, lane = tid & 63;
  const int j = lane & 31, half = lane >> 5, b = blockIdx.x;
  float4 etr[8];
  LOAD_ETR(etr, trans, lane)
  const float cvj = cvec[j];
  float* eswb = esb[w];

  { // width 8192: node 16384+n, n=b*16+w, children = leaves 2n,2n+1
    const int n = b * 16 + w;
    float cs = E0[(size_t)(2 * n + half) * LL + j] + cvj;
    float ep = E0[(size_t)(16384 + n) * LL + j];
    float o = node_combine(cs, ep, cvj, etr, eswb, lane);
    if (lane < 32) l1[w][j] = o;
  }
  __syncthreads();
  if (w < 8) { // width 4096: node 24576 + b*8 + w
    float cs = l1[2 * w + half][j];
    float ep = E0[(size_t)(24576 + b * 8 + w) * LL + j];
    float o = node_combine(cs, ep, cvj, etr, eswb, lane);
    if (lane < 32) l2[w][j] = o;
  }
  __syncthreads();
  if (w < 4) { // width 2048: node 28672 + b*4 + w
    float cs = l2[2 * w + half][j];
    float ep = E0[(size_t)(28672 + b * 4 + w) * LL + j];
    float o = node_combine(cs, ep, cvj, etr, eswb, lane);
    if (lane < 32) l3[w][j] = o;
  }
  __syncthreads();
  if (w < 2) { // width 1024: node 30720 + b*2 + w
    float cs = l3[2 * w + half][j];
    float ep = E0[(size_t)(30720 + b * 2 + w) * LL + j];
    float o = node_combine(cs, ep, cvj, etr, eswb, lane);
    if (lane < 32) l4[w][j] = o;
  }
  __syncthreads();
  if (w == 0) { // width 512: node 31744 + b -> S5[b]
    float cs = l4[half][j];
    float ep = E0[(size_t)(31744 + b) * LL + j];
    float o = node_combine(cs, ep, cvj, etr, eswb, lane);
    if (lane < 32) S5[(size_t)b * LL + j] = o;
  }
}

// T2: widths 256..1 in one block (ping-pong LDS), root -> out.
__global__ __launch_bounds__(1024) void tree2_kernel(
    const float* __restrict__ E0, const float* __restrict__ cvec,
    const float* __restrict__ trans, const float* __restrict__ S5,
    float* __restrict__ out) {
  __shared__ float esb[16][64];
  __shared__ float bufA[256][LL];   // 32KB
  __shared__ float bufB[128][LL];   // 16KB
  const int tid = threadIdx.x, w = tid >> 6, lane = tid & 63;
  const int j = lane & 31, half = lane >> 5;
  float4 etr[8];
  LOAD_ETR(etr, trans, lane)
  const float cvj = cvec[j];
  float* eswb = esb[w];

  { // width 256: nodes 32256+n, children S5[2n+half] (global, prefetched)
    float cs[16], ep[16];
    #pragma unroll
    for (int t = 0; t < 16; ++t) {
      const int n = w * 16 + t;
      cs[t] = S5[(size_t)(2 * n + half) * LL + j];
      ep[t] = E0[(size_t)(32256 + n) * LL + j];
    }
    #pragma unroll
    for (int t = 0; t < 16; ++t) {
      float o = node_combine(cs[t], ep[t], cvj, etr, eswb, lane);
      if (lane < 32) bufA[w * 16 + t][j] = o;
    }
  }
  __syncthreads();
  { // width 128: nodes 32512+n, children bufA
    float cs[8], ep[8];
    #pragma unroll
    for (int t = 0; t < 8; ++t) {
      const int n = w * 8 + t;
      cs[t] = bufA[2 * n + half][j];
      ep[t] = E0[(size_t)(32512 + n) * LL + j];
    }
    #pragma unroll
    for (int t = 0; t < 8; ++t) {
      float o = node_combine(cs[t], ep[t], cvj, etr, eswb, lane);
      if (lane < 32) bufB[w * 8 + t][j] = o;
    }
  }
  __syncthreads();
  { // width 64: nodes 32640+n, children bufB -> bufA rows 0..63
    float cs[4], ep[4];
    #pragma unroll
    for (int t = 0; t < 4; ++t) {
      const int n = w * 4 + t;
      cs[t] = bufB[2 * n + half][j];
      ep[t] = E0[(size_t)(32640 + n) * LL + j];
    }
    #pragma unroll
    for (int t = 0; t < 4; ++t) {
      float o = node_combine(cs[t], ep[t], cvj, etr, eswb, lane);
      if (lane < 32) bufA[w * 4 + t][j] = o;
    }
  }
  __syncthreads();
  { // width 32: nodes 32704+n, children bufA -> bufB rows 0..31
    float cs[2], ep[2];
    #pragma unroll
    for (int t = 0; t < 2; ++t) {
      const int n = w * 2 + t;
      cs[t] = bufA[2 * n + half][j];
      ep[t] = E0[(size_t)(32704 + n) * LL + j];
    }
    #pragma unroll
    for (int t = 0; t < 2; ++t) {
      float o = node_combine(cs[t], ep[t], cvj, etr, eswb, lane);
      if (lane < 32) bufB[w * 2 + t][j] = o;
    }
  }
  __syncthreads();
  { // width 16: nodes 32736+w, children bufB -> bufA rows 0..15
    float cs = bufB[2 * w + half][j];
    float ep = E0[(size_t)(32736 + w) * LL + j];
    float o = node_combine(cs, ep, cvj, etr, eswb, lane);
    if (lane < 32) bufA[w][j] = o;
  }
  __syncthreads();
  if (w < 8) { // width 8: nodes 32752+w -> bufB rows 0..7
    float cs = bufA[2 * w + half][j];
    float ep = E0[(size_t)(32752 + w) * LL + j];
    float o = node_combine(cs, ep, cvj, etr, eswb, lane);
    if (lane < 32) bufB[w][j] = o;
  }
  __syncthreads();
  if (w < 4) { // width 4: nodes 32760+w -> bufA rows 0..3
    float cs = bufB[2 * w + half][j];
    float ep = E0[(size_t)(32760 + w) * LL + j];
    float o = node_combine(cs, ep, cvj, etr, eswb, lane);
    if (lane < 32) bufA[w][j] = o;
  }
  __syncthreads();
  if (w < 2) { // width 2: nodes 32764+w -> bufB rows 0..1
    float cs = bufA[2 * w + half][j];
    float ep = E0[(size_t)(32764 + w) * LL + j];
    float o = node_combine(cs, ep, cvj, etr, eswb, lane);
    if (lane < 32) bufB[w][j] = o;
  }
  __syncthreads();
  if (w == 0) { // root: node 32766 -> out
    float cs = bufB[half][j];
    float ep = E0[(size_t)32766 * LL + j];
    float o = node_combine(cs, ep, cvj, etr, eswb, lane);
    if (lane < 32) out[j] = o;
  }
}

extern "C" void kernel_launch(void* const* d_in, const int* in_sizes, int n_in,
                              void* d_out, int out_size, void* d_ws, size_t ws_size,
                              hipStream_t stream) {
  const float* hidden = (const float*)d_in[0];
  const float* trans  = (const float*)d_in[1];
  const float* Wp     = (const float*)d_in[2];
  const float* bp     = (const float*)d_in[3];

  float* ws    = (float*)d_ws;
  float* E0    = ws;                               // NN*32 f32
  float* gpart = E0 + (size_t)NN * LL;             // 2048*32 f32
  float* cvecb = gpart + (size_t)2048 * LL;        // 32 f32
  float* S5    = cvecb + 32;                       // 512*32 f32
  short* Wpk   = (short*)(S5 + 512 * LL);          // 65536 bf16

  pack_kernel<<<64, 256, 0, stream>>>(Wp, Wpk);
  gemm_kernel<<<512, 256, 0, stream>>>(hidden, Wpk, E0, gpart);
  cvec_kernel<<<32, 256, 0, stream>>>(bp, gpart, cvecb);
  tree1_kernel<<<512, 1024, 0, stream>>>(E0, cvecb, trans, S5);   // 8192..512
  tree2_kernel<<<1, 1024, 0, stream>>>(E0, cvecb, trans, S5, (float*)d_out); // 256..1
}